// Round 8
// baseline (255.973 us; speedup 1.0000x reference)
//
#include <hip/hip_runtime.h>
#include <math.h>

// Problem shape (fixed by reference): x [32,256,64,64] f32, W [1,2,7,7], b [1]
constexpr int B_  = 32;
constexpr int C_  = 256;
constexpr int H_  = 64;
constexpr int W_  = 64;
constexpr int HW_ = H_ * W_;              // 4096
constexpr size_t CHW_ = (size_t)C_ * HW_; // 1048576

typedef float v4f __attribute__((ext_vector_type(4)));  // native vec for nontemporal store

// ---------------------------------------------------------------------------
// Round-8 structure: back to two kernels, each shaped for its regime.
// Round-7 post-mortem: the fused kernel was latency-bound (2.7 TB/s HBM, 5.7%
// VALU, 19% occupancy) — 512 big blocks with serial load->conv->store phases
// can't keep the memory pipe full at 2 blocks/CU. Fix = give the streaming
// work 8 co-resident blocks/CU and let the tiny conv be recomputed
// redundantly instead of creating any dependency or occupancy cost.
//   k1 pool: reads x cold from HBM once (134 MB), writes 1 MB pool, AND
//            leaves x resident in L3 (134 < 256 MB) for k2.
//   k2 conv+scale: 2048 blocks x 256 thr (channel-split x4 per (b,h-quad)):
//            stage 10-row pool halo (5 KB), conv 7x7 -> sigmoid (256 outputs,
//            one/thread, redundant x4 across channel-split siblings), then
//            stream 64 channels: x from L3, nontemporal stores to HBM.
// ---------------------------------------------------------------------------

// Kernel 1 (harness-proven in Round 3): channel-wise max+mean pool.
// Block = (b, h-quad): rows h0..h0+3, all 256 channels. 512 threads = 8 waves.
// Wave w: channels [w*32, w*32+32); lane = float4 position in the contiguous
// 4-row span -> every global load is 64 lanes x 16 B = 1 KB contiguous.
__global__ __launch_bounds__(512) void pool_kernel(const float* __restrict__ x,
                                                   float* __restrict__ pool) {
    const int blk  = blockIdx.x;       // 0 .. 511
    const int b    = blk >> 4;
    const int h0   = (blk & 15) * 4;
    const int tid  = threadIdx.x;
    const int wv   = tid >> 6;         // wave 0..7
    const int lane = tid & 63;

    const float* base = x + (size_t)b * CHW_ + (size_t)(wv * 32) * HW_ + h0 * W_ + lane * 4;
    float4 v  = *(const float4*)base;
    float4 mx = v, sm = v;
#pragma unroll
    for (int c = 1; c < 32; ++c) {
        float4 u = *(const float4*)(base + (size_t)c * HW_);
        mx.x = fmaxf(mx.x, u.x); mx.y = fmaxf(mx.y, u.y);
        mx.z = fmaxf(mx.z, u.z); mx.w = fmaxf(mx.w, u.w);
        sm.x += u.x; sm.y += u.y; sm.z += u.z; sm.w += u.w;
    }

    __shared__ __align__(16) float4 lmax[8][64];   // [wave][lane]  4 KiB
    __shared__ __align__(16) float4 lsum[8][64];   // 4 KiB
    lmax[wv][lane] = mx;
    lsum[wv][lane] = sm;
    __syncthreads();

    if (tid < 64) {                    // one thread per span slot: 8-way combine
        float4 M = lmax[0][tid], S = lsum[0][tid];
#pragma unroll
        for (int g = 1; g < 8; ++g) {
            float4 m2 = lmax[g][tid], s2 = lsum[g][tid];
            M.x = fmaxf(M.x, m2.x); M.y = fmaxf(M.y, m2.y);
            M.z = fmaxf(M.z, m2.z); M.w = fmaxf(M.w, m2.w);
            S.x += s2.x; S.y += s2.y; S.z += s2.z; S.w += s2.w;
        }
        const float inv = 1.0f / 256.0f;
        float4 A = make_float4(S.x * inv, S.y * inv, S.z * inv, S.w * inv);
        // slot -> (row r, col): linear offset tid*4 within the 4-row span
        const int r   = tid >> 4;
        const int col = (tid & 15) * 4;
        // pool layout [B][2][H][W]: plane 0 = max, plane 1 = avg (concat order)
        float* pm = pool + (size_t)b * 2 * HW_ + (h0 + r) * W_ + col;
        *(float4*)pm         = M;
        *(float4*)(pm + HW_) = A;
    }
}

// Kernel 2: conv 7x7 + bias + sigmoid (redundant per channel-split sibling)
// then scale 64 channels. Block = (b, h-quad, cs): 2048 blocks x 256 threads
// (4 waves) -> ~8 blocks/CU co-resident; per-CU block queue hides each
// block's barrier/conv latency behind siblings' streaming.
__global__ __launch_bounds__(256) void conv_scale_kernel(const float* __restrict__ x,
                                                         const float* __restrict__ pool,
                                                         const float* __restrict__ Wp,
                                                         const float* __restrict__ bp,
                                                         float* __restrict__ out) {
    const int blk = blockIdx.x;        // 0..2047
    const int cs  = blk & 3;           // channel split: channels cs*64 .. cs*64+63
    const int bh  = blk >> 2;          // 0..511
    const int b   = bh >> 4;
    const int h0  = (bh & 15) * 4;
    const int tid = threadIdx.x;

    __shared__ float sw[98];
    __shared__ __align__(16) float spool[2][10][64];  // halo rows h0-3..h0+6
    __shared__ __align__(16) float ssa[256];          // sigmoid(conv), [r][col]

    if (tid < 98) sw[tid] = Wp[tid];
    for (int idx = tid; idx < 1280; idx += 256) {
        const int plane = idx / 640;
        const int rem   = idx - plane * 640;
        const int r     = rem >> 6;    // 0..9
        const int w     = rem & 63;
        const int hh    = h0 + r - 3;
        spool[plane][r][w] = (hh >= 0 && hh < H_)
            ? pool[((size_t)b * 2 + plane) * HW_ + hh * W_ + w] : 0.0f;
    }
    __syncthreads();

    {                                  // one conv output per thread (all 256)
        const int r   = tid >> 6;      // output row 0..3 (global h0+r)
        const int col = tid & 63;
        float acc = bp[0];
#pragma unroll
        for (int p = 0; p < 2; ++p) {
            const float* wc = sw + p * 49;
#pragma unroll
            for (int kh = 0; kh < 7; ++kh) {
                const float* prow = &spool[p][r + kh][0];  // halo row r+kh
#pragma unroll
                for (int kw = 0; kw < 7; ++kw) {
                    const int ww = col + kw - 3;
                    if (ww >= 0 && ww < W_)
                        acc = fmaf(prow[ww], wc[kh * 7 + kw], acc);
                }
            }
        }
        ssa[tid] = 1.0f / (1.0f + expf(-acc));
    }
    __syncthreads();

    // Scale: wave wv (0..3) -> 16 contiguous channels cs*64 + wv*16 + k.
    // lane = float4 position in the contiguous 4-row span (rows h0..h0+3):
    // element lane*4+j -> row lane>>4, col (lane&15)*4+j == ssa float4 [lane].
    const int lane = tid & 63;
    const int wv   = tid >> 6;
    const float4 sv = ((const float4*)ssa)[lane];
    const size_t spanbase = (size_t)b * CHW_
                          + (size_t)(cs * 64 + wv * 16) * HW_
                          + (size_t)h0 * W_ + lane * 4;
    const float* xb = x + spanbase;
    float*       ob = out + spanbase;
#pragma unroll
    for (int k = 0; k < 16; ++k) {     // 1 KB coalesced load + NT store per instr
        const float4 xv = *(const float4*)(xb + (size_t)k * HW_);
        v4f ov;
        ov.x = xv.x * sv.x; ov.y = xv.y * sv.y;
        ov.z = xv.z * sv.z; ov.w = xv.w * sv.w;
        __builtin_nontemporal_store(ov, (v4f*)(ob + (size_t)k * HW_));
    }
}

extern "C" void kernel_launch(void* const* d_in, const int* in_sizes, int n_in,
                              void* d_out, int out_size, void* d_ws, size_t ws_size,
                              hipStream_t stream) {
    const float* x  = (const float*)d_in[0];
    const float* Wp = (const float*)d_in[1];
    const float* bp = (const float*)d_in[2];
    float* out = (float*)d_out;

    // workspace: pool [32][2][64][64]  (1 MB)
    float* pool = (float*)d_ws;

    pool_kernel<<<B_ * (H_ / 4), 512, 0, stream>>>(x, pool);
    conv_scale_kernel<<<B_ * (H_ / 4) * 4, 256, 0, stream>>>(x, pool, Wp, bp, out);
}